// Round 4
// baseline (632.331 us; speedup 1.0000x reference)
//
#include <hip/hip_runtime.h>
#include <math.h>

#define B_ 64
#define N_ 128
#define F_ 128
#define R_ 64
#define H_ 256
#define L_ 3
#define M_ (B_*N_)   // 8192 rows

#define DS_PAD 72    // ds_lds row stride (shorts)
#define X_PAD 136    // x_lds row stride
#define P_PAD 264    // p_lds row stride

#define PREP_NBLK   48
#define COMB_BID    48
#define STREAM_BID0 49
#define NSTREAM     (M_/8)    // 1024 stream blocks, 8 rows each
#define NGROUP      (M_/32)   // 256 layer groups
#define WREADY_TARGET 49u

typedef short bf16x8 __attribute__((ext_vector_type(8)));
typedef float f32x4 __attribute__((ext_vector_type(4)));

__device__ __forceinline__ unsigned short f2bf(float f) {
    unsigned int u = __float_as_uint(f);
    u += 0x7FFF + ((u >> 16) & 1);   // round-to-nearest-even
    return (unsigned short)(u >> 16);
}

__device__ __forceinline__ float tanh_fast(float h) {
    float a = fabsf(h);
    float e = __expf(-2.0f * a);
    float t = (1.0f - e) * __builtin_amdgcn_rcpf(1.0f + e);
    return copysignf(t, h);
}

// one kernel: [0,48) weight-prep | 48 comb+out-init | [49,49+1024) dsum streams,
// every 4th stream block continues into the fused 3-layer MFMA phase for its 32-row group.
__global__ __launch_bounds__(512, 2)
void fused_kernel(const float* __restrict__ x,
                  const float* __restrict__ dist,
                  const float* __restrict__ wcf_w,
                  const float* __restrict__ biascf,
                  const float* __restrict__ wdf_w,
                  const float* __restrict__ biasdf,
                  const float* __restrict__ wfc_w,
                  const float* __restrict__ fc0_w, const float* __restrict__ fc0_b,
                  const float* __restrict__ out_w, const float* __restrict__ out_b,
                  unsigned short* __restrict__ wcfb,
                  unsigned short* __restrict__ wdfb,
                  unsigned short* __restrict__ wfcb,
                  float* __restrict__ wcomb,
                  unsigned short* __restrict__ dsumb,
                  unsigned int* __restrict__ cnt,
                  unsigned int* __restrict__ wready,
                  float* __restrict__ out) {
    const int bid = blockIdx.x;
    const int t   = threadIdx.x;

    if (bid < PREP_NBLK) {
        // fp32 -> bf16 for the 3 stacked weight tensors
        const int NCF = L_*H_*F_/4;  // 24576 float4
        const int NDF = L_*H_*R_/4;  // 12288
        const int NFC = L_*F_*H_/4;  // 24576
        const int total = NCF + NDF + NFC;
        for (int i = bid*512 + t; i < total; i += PREP_NBLK*512) {
            const float4* src; unsigned short* dst; int k;
            if (i < NCF)           { src = (const float4*)wcf_w; dst = wcfb; k = i; }
            else if (i < NCF+NDF)  { src = (const float4*)wdf_w; dst = wdfb; k = i-NCF; }
            else                   { src = (const float4*)wfc_w; dst = wfcb; k = i-NCF-NDF; }
            float4 v = src[k];
            ushort4 o; o.x=f2bf(v.x); o.y=f2bf(v.y); o.z=f2bf(v.z); o.w=f2bf(v.w);
            ((ushort4*)dst)[k] = o;
        }
        __syncthreads();
        __threadfence();
        if (t == 0) __hip_atomic_fetch_add(wready, 1u, __ATOMIC_RELEASE, __HIP_MEMORY_SCOPE_AGENT);
        return;
    }
    if (bid == COMB_BID) {
        if (t < 128) {
            float s = 0.f;
            #pragma unroll 8
            for (int c = 0; c < 256; ++c) s += out_w[c] * fc0_w[c*128 + t];
            wcomb[t] = s;
        } else if (t < 192) {
            float bb = out_b[0];
            #pragma unroll 8
            for (int c = 0; c < 256; ++c) bb += out_w[c] * fc0_b[c];
            out[t - 128] = bb;   // init; runners atomicAdd on top (gated on wready)
        }
        __syncthreads();
        __threadfence();
        if (t == 0) __hip_atomic_fetch_add(wready, 1u, __ATOMIC_RELEASE, __HIP_MEMORY_SCOPE_AGENT);
        return;
    }

    // ---- stream phase: 8 waves, 1 row per wave; wave-load = 64 contiguous float4 (1 KB) ----
    const int i    = bid - STREAM_BID0;        // 0..1023
    const int w    = t >> 6, lane = t & 63;
    const int lr   = lane & 15, lg = lane >> 4;
    {
        const int row = i*8 + w;
        const float4* src4 = (const float4*)(dist + (size_t)row * (N_*R_));
        float4 a = {0.f,0.f,0.f,0.f};
        #pragma unroll 8
        for (int ii = 0; ii < 32; ++ii) {
            float4 v = src4[ii*64 + lane];
            a.x += v.x; a.y += v.y; a.z += v.z; a.w += v.w;
        }
        // butterfly over jg = lane>>4 (lanes 16/32 apart share the same q = lane&15)
        a.x += __shfl_xor(a.x, 16); a.y += __shfl_xor(a.y, 16);
        a.z += __shfl_xor(a.z, 16); a.w += __shfl_xor(a.w, 16);
        a.x += __shfl_xor(a.x, 32); a.y += __shfl_xor(a.y, 32);
        a.z += __shfl_xor(a.z, 32); a.w += __shfl_xor(a.w, 32);
        if (lane < 16) {
            ushort4 o; o.x=f2bf(a.x); o.y=f2bf(a.y); o.z=f2bf(a.z); o.w=f2bf(a.w);
            ((ushort4*)(dsumb + (size_t)row * R_))[lane] = o;
        }
    }
    __syncthreads();
    __threadfence();

    const int g = i >> 2;                      // 32-row group
    if ((i & 3) != 3) {
        if (t == 0) __hip_atomic_fetch_add(&cnt[g], 1u, __ATOMIC_RELEASE, __HIP_MEMORY_SCOPE_AGENT);
        return;
    }
    // runner: wait for sibling dsum blocks (lower bids) + weight prep (bids 0..48)
    if (t == 0) {
        __hip_atomic_fetch_add(&cnt[g], 1u, __ATOMIC_RELEASE, __HIP_MEMORY_SCOPE_AGENT);
        while (__hip_atomic_load(&cnt[g], __ATOMIC_ACQUIRE, __HIP_MEMORY_SCOPE_AGENT) < 4u ||
               __hip_atomic_load(wready,  __ATOMIC_ACQUIRE, __HIP_MEMORY_SCOPE_AGENT) < WREADY_TARGET)
            __builtin_amdgcn_s_sleep(2);
    }
    __syncthreads();
    __threadfence();

    // ---- layer phase for rows g*32 .. g*32+31 ----
    __shared__ __align__(16) unsigned short ds_lds[32][DS_PAD];
    __shared__ __align__(16) unsigned short x_lds[32][X_PAD];
    __shared__ __align__(16) unsigned short p_lds[32][P_PAD];

    {
        const int row16 = t >> 4, q = t & 15;
        const float4* xs = (const float4*)(x + (size_t)(g*32 + row16)*F_ + q*8);
        float4 xv0 = xs[0], xv1 = xs[1];
        bf16x8 xb;
        xb[0]=f2bf(xv0.x); xb[1]=f2bf(xv0.y); xb[2]=f2bf(xv0.z); xb[3]=f2bf(xv0.w);
        xb[4]=f2bf(xv1.x); xb[5]=f2bf(xv1.y); xb[6]=f2bf(xv1.z); xb[7]=f2bf(xv1.w);
        *(bf16x8*)&x_lds[row16][q*8] = xb;
        if (t < 256) {
            const uint4* dsrc = (const uint4*)(dsumb + (size_t)(g*32 + (t>>3))*R_);
            uint4 v = dsrc[t & 7];
            *(uint4*)&ds_lds[t>>3][(t&7)*8] = v;
        }
    }
    __syncthreads();

    float pool_acc = 0.f;

    #pragma unroll 1
    for (int l = 0; l < L_; ++l) {
        const unsigned short* wcf = wcfb + l*H_*F_;
        const unsigned short* wdf = wdfb + l*H_*R_;
        const unsigned short* wfc = wfcb + l*F_*H_;

        // A-fragments for BOTH 16-row halves
        bf16x8 xa[2][4], da[2][2];
        #pragma unroll
        for (int mh = 0; mh < 2; ++mh) {
            #pragma unroll
            for (int kc = 0; kc < 4; ++kc)
                xa[mh][kc] = *(const bf16x8*)&x_lds[mh*16 + lr][kc*32 + lg*8];
            #pragma unroll
            for (int kc = 0; kc < 2; ++kc)
                da[mh][kc] = *(const bf16x8*)&ds_lds[mh*16 + lr][kc*32 + lg*8];
        }

        // stage 1: wave owns H-cols [w*32, w*32+32); B-frags loaded once, used by both halves
        #pragma unroll
        for (int nt = 0; nt < 2; ++nt) {
            const int ncol = w*32 + nt*16 + lr;
            bf16x8 bcfv[4], bdfv[2];
            #pragma unroll
            for (int kc = 0; kc < 4; ++kc)
                bcfv[kc] = *(const bf16x8*)(wcf + (size_t)ncol*F_ + kc*32 + lg*8);
            #pragma unroll
            for (int kc = 0; kc < 2; ++kc)
                bdfv[kc] = *(const bf16x8*)(wdf + (size_t)ncol*R_ + kc*32 + lg*8);
            const float bc = biascf[l*H_ + ncol];
            const float bd = biasdf[l*H_ + ncol] * 128.0f;
            #pragma unroll
            for (int mh = 0; mh < 2; ++mh) {
                f32x4 acf = {0.f,0.f,0.f,0.f}, adf = {0.f,0.f,0.f,0.f};
                #pragma unroll
                for (int kc = 0; kc < 4; ++kc)
                    acf = __builtin_amdgcn_mfma_f32_16x16x32_bf16(xa[mh][kc], bcfv[kc], acf, 0, 0, 0);
                #pragma unroll
                for (int kc = 0; kc < 2; ++kc)
                    adf = __builtin_amdgcn_mfma_f32_16x16x32_bf16(da[mh][kc], bdfv[kc], adf, 0, 0, 0);
                #pragma unroll
                for (int j = 0; j < 4; ++j) {
                    float p = (acf[j] + bc) * (adf[j] + bd);
                    p_lds[mh*16 + lg*4 + j][ncol] = f2bf(p);
                }
            }
        }
        __syncthreads();

        // stage 2: wave owns F-cols [w*16, w*16+16); one B-load feeds both halves
        const int ncol2 = w*16 + lr;
        f32x4 ah[2] = {{0,0,0,0},{0,0,0,0}};
        #pragma unroll
        for (int kc = 0; kc < 8; ++kc) {
            bf16x8 b = *(const bf16x8*)(wfc + (size_t)ncol2*H_ + kc*32 + lg*8);
            #pragma unroll
            for (int mh = 0; mh < 2; ++mh) {
                bf16x8 ap = *(const bf16x8*)&p_lds[mh*16 + lr][kc*32 + lg*8];
                ah[mh] = __builtin_amdgcn_mfma_f32_16x16x32_bf16(ap, b, ah[mh], 0, 0, 0);
            }
        }
        __syncthreads();   // p_lds consumed

        if (l < L_-1) {
            #pragma unroll
            for (int mh = 0; mh < 2; ++mh)
                #pragma unroll
                for (int j = 0; j < 4; ++j) {
                    float h = ah[mh][j];
                    float xo = h + tanh_fast(h);
                    x_lds[mh*16 + lg*4 + j][ncol2] = f2bf(xo);
                }
            __syncthreads();
        } else {
            const float wc = wcomb[ncol2];
            #pragma unroll
            for (int mh = 0; mh < 2; ++mh)
                #pragma unroll
                for (int j = 0; j < 4; ++j) {
                    float h = ah[mh][j];
                    pool_acc += (h + tanh_fast(h)) * wc;
                }
        }
    }

    // block reduce + one atomicAdd into out[b]  (4 groups per batch)
    float* red = (float*)&p_lds[0][0];
    red[t] = pool_acc;
    __syncthreads();
    #pragma unroll
    for (int s = 256; s > 0; s >>= 1) {
        if (t < s) red[t] += red[t + s];
        __syncthreads();
    }
    if (t == 0) atomicAdd(&out[g >> 2], red[0]);
}

extern "C" void kernel_launch(void* const* d_in, const int* in_sizes, int n_in,
                              void* d_out, int out_size, void* d_ws, size_t ws_size,
                              hipStream_t stream) {
    const float* x     = (const float*)d_in[0];
    const float* dist  = (const float*)d_in[1];
    const float* wcf_w = (const float*)d_in[2];
    const float* wcf_b = (const float*)d_in[3];
    const float* wdf_w = (const float*)d_in[4];
    const float* wdf_b = (const float*)d_in[5];
    const float* wfc_w = (const float*)d_in[6];
    const float* fc0_w = (const float*)d_in[7];
    const float* fc0_b = (const float*)d_in[8];
    const float* out_w = (const float*)d_in[9];
    const float* out_b = (const float*)d_in[10];
    float* out = (float*)d_out;

    char* ws = (char*)d_ws;
    unsigned short* wcfb  = (unsigned short*)(ws);                  // 196608 B
    unsigned short* wdfb  = (unsigned short*)(ws + 196608u);        //  98304 B
    unsigned short* wfcb  = (unsigned short*)(ws + 294912u);        // 196608 B
    float*          wcomb = (float*)(ws + 491520u);                 //    512 B
    unsigned short* dsumb = (unsigned short*)(ws + 492032u);        // 1 MB
    unsigned int*   cnt   = (unsigned int*)(ws + 1540608u);         // 1024 B
    unsigned int*   wrdy  = (unsigned int*)(ws + 1541632u);         //    4 B

    // zero the flags every call (harness does not re-poison between replays)
    hipMemsetAsync(ws + 1540608u, 0, 1028, stream);

    fused_kernel<<<STREAM_BID0 + NSTREAM, 512, 0, stream>>>(
        x, dist, wcf_w, wcf_b, wdf_w, wdf_b, wfc_w,
        fc0_w, fc0_b, out_w, out_b,
        wcfb, wdfb, wfcb, wcomb, dsumb, cnt, wrdy, out);
}

// Round 5
// 109.984 us; speedup vs baseline: 5.7493x; 5.7493x over previous
//
#include <hip/hip_runtime.h>
#include <math.h>

#define B_ 64
#define N_ 128
#define F_ 128
#define R_ 64
#define H_ 256
#define L_ 3
#define M_ (B_*N_)     // 8192 rows
#define RPB 16         // rows per block
#define NBLK (M_/RPB)  // 512 blocks

#define DS_PAD 72      // ds_lds row stride (shorts), 144 B = 9*16
#define X_PAD 136      // x_lds row stride, 272 B = 17*16
#define P_PAD 264      // p_lds row stride, 528 B = 33*16

typedef short bf16x8 __attribute__((ext_vector_type(8)));
typedef float f32x4 __attribute__((ext_vector_type(4)));

__device__ __forceinline__ unsigned short f2bf(float f) {
    unsigned int u = __float_as_uint(f);
    u += 0x7FFF + ((u >> 16) & 1);   // round-to-nearest-even
    return (unsigned short)(u >> 16);
}

__device__ __forceinline__ float tanh_fast(float h) {
    float a = fabsf(h);
    float e = __expf(-2.0f * a);
    float t = (1.0f - e) * __builtin_amdgcn_rcpf(1.0f + e);
    return copysignf(t, h);
}

// load 8 consecutive fp32 weights, convert to bf16x8 MFMA B-fragment
__device__ __forceinline__ bf16x8 ld_w_bf16(const float* __restrict__ p) {
    float4 v0 = ((const float4*)p)[0];
    float4 v1 = ((const float4*)p)[1];
    bf16x8 r;
    r[0]=f2bf(v0.x); r[1]=f2bf(v0.y); r[2]=f2bf(v0.z); r[3]=f2bf(v0.w);
    r[4]=f2bf(v1.x); r[5]=f2bf(v1.y); r[6]=f2bf(v1.z); r[7]=f2bf(v1.w);
    return r;
}

// ---- mega: per block (16 rows): dsum stream + 3 fused DTNN layers + pooled partial ----
// 512 threads = 8 waves. No cross-block communication whatsoever.
__global__ __launch_bounds__(512, 4)
void mega_kernel(const float* __restrict__ x,
                 const float* __restrict__ dist,
                 const float* __restrict__ wcf_w,
                 const float* __restrict__ biascf,
                 const float* __restrict__ wdf_w,
                 const float* __restrict__ biasdf,
                 const float* __restrict__ wfc_w,
                 const float* __restrict__ fc0_w,
                 const float* __restrict__ out_w,
                 float* __restrict__ partial) {
    __shared__ __align__(16) unsigned short ds_lds[RPB][DS_PAD];
    __shared__ __align__(16) unsigned short x_lds[RPB][X_PAD];
    __shared__ __align__(16) unsigned short p_lds[RPB][P_PAD];
    __shared__ float wcomb_lds[128];

    const int blk  = blockIdx.x;
    const int t    = threadIdx.x;
    const int w    = t >> 6, lane = t & 63;
    const int lr   = lane & 15, lg = lane >> 4;

    // ---- Phase A: dsum for this block's 16 rows (2 rows per wave, contiguous 32 KB streams) ----
    #pragma unroll
    for (int rr = 0; rr < 2; ++rr) {
        const int rloc = w*2 + rr;
        const float4* src = (const float4*)(dist + (size_t)(blk*RPB + rloc) * (N_*R_));
        float4 a0 = {0.f,0.f,0.f,0.f}, a1 = {0.f,0.f,0.f,0.f};
        #pragma unroll
        for (int ii = 0; ii < 32; ii += 2) {
            float4 v0 = src[ii*64 + lane];
            float4 v1 = src[ii*64 + 64 + lane];
            a0.x += v0.x; a0.y += v0.y; a0.z += v0.z; a0.w += v0.w;
            a1.x += v1.x; a1.y += v1.y; a1.z += v1.z; a1.w += v1.w;
        }
        float4 a;
        a.x = a0.x + a1.x; a.y = a0.y + a1.y; a.z = a0.z + a1.z; a.w = a0.w + a1.w;
        // butterfly over jg = lane>>4 (lanes 16/32 apart share the same q = lane&15)
        a.x += __shfl_xor(a.x, 16); a.y += __shfl_xor(a.y, 16);
        a.z += __shfl_xor(a.z, 16); a.w += __shfl_xor(a.w, 16);
        a.x += __shfl_xor(a.x, 32); a.y += __shfl_xor(a.y, 32);
        a.z += __shfl_xor(a.z, 32); a.w += __shfl_xor(a.w, 32);
        if (lane < 16) {
            ushort4 o; o.x=f2bf(a.x); o.y=f2bf(a.y); o.z=f2bf(a.z); o.w=f2bf(a.w);
            *(ushort4*)&ds_lds[rloc][lane*4] = o;
        }
    }
    // x -> bf16 -> LDS (16 rows x 32 float4)
    {
        const int row = t >> 5, c = t & 31;
        float4 v = ((const float4*)(x + (size_t)(blk*RPB + row)*F_))[c];
        ushort4 o; o.x=f2bf(v.x); o.y=f2bf(v.y); o.z=f2bf(v.z); o.w=f2bf(v.w);
        *(ushort4*)&x_lds[row][c*4] = o;
    }
    __syncthreads();

    // ---- wcomb[f] = sum_c out_w[c]*fc0_w[c,f] (block-local recompute, hidden under streams) ----
    {
        float* wred = (float*)&p_lds[0][0];   // 4*128 floats scratch
        const int f = t & 127, cc = t >> 7;   // cc in 0..3
        float s = 0.f;
        #pragma unroll 16
        for (int c = cc*64; c < cc*64 + 64; ++c) s += out_w[c] * fc0_w[c*128 + f];
        wred[cc*128 + f] = s;
        __syncthreads();
        if (t < 128) wcomb_lds[t] = wred[t] + wred[128+t] + wred[256+t] + wred[384+t];
        __syncthreads();
    }

    float pool_acc = 0.f;

    #pragma unroll 1
    for (int l = 0; l < L_; ++l) {
        // A-fragments: lane holds A[lr][kc*32 + lg*8 + j]
        bf16x8 xa[4], da[2];
        #pragma unroll
        for (int kc = 0; kc < 4; ++kc)
            xa[kc] = *(const bf16x8*)&x_lds[lr][kc*32 + lg*8];
        #pragma unroll
        for (int kc = 0; kc < 2; ++kc)
            da[kc] = *(const bf16x8*)&ds_lds[lr][kc*32 + lg*8];

        // stage 1: wave owns H-cols [w*32, w*32+32)
        #pragma unroll
        for (int nt = 0; nt < 2; ++nt) {
            const int ncol = w*32 + nt*16 + lr;
            f32x4 acf = {0.f,0.f,0.f,0.f}, adf = {0.f,0.f,0.f,0.f};
            #pragma unroll
            for (int kc = 0; kc < 4; ++kc) {
                bf16x8 b = ld_w_bf16(wcf_w + ((size_t)(l*H_ + ncol))*F_ + kc*32 + lg*8);
                acf = __builtin_amdgcn_mfma_f32_16x16x32_bf16(xa[kc], b, acf, 0, 0, 0);
            }
            #pragma unroll
            for (int kc = 0; kc < 2; ++kc) {
                bf16x8 b = ld_w_bf16(wdf_w + ((size_t)(l*H_ + ncol))*R_ + kc*32 + lg*8);
                adf = __builtin_amdgcn_mfma_f32_16x16x32_bf16(da[kc], b, adf, 0, 0, 0);
            }
            const float bc = biascf[l*H_ + ncol];
            const float bd = biasdf[l*H_ + ncol] * 128.0f;   // n * Wdf_b, n = 128
            #pragma unroll
            for (int j = 0; j < 4; ++j) {
                float p = (acf[j] + bc) * (adf[j] + bd);
                p_lds[lg*4 + j][ncol] = f2bf(p);
            }
        }
        __syncthreads();

        // stage 2: wave owns F-cols [w*16, w*16+16); h(16x128) = p(16x256) @ Wfc^T
        const int ncol2 = w*16 + lr;
        f32x4 ah = {0.f,0.f,0.f,0.f};
        #pragma unroll
        for (int kc = 0; kc < 8; ++kc) {
            bf16x8 bw = ld_w_bf16(wfc_w + ((size_t)(l*F_ + ncol2))*H_ + kc*32 + lg*8);
            bf16x8 ap = *(const bf16x8*)&p_lds[lr][kc*32 + lg*8];
            ah = __builtin_amdgcn_mfma_f32_16x16x32_bf16(ap, bw, ah, 0, 0, 0);
        }
        __syncthreads();   // p_lds consumed by all waves

        if (l < L_-1) {
            #pragma unroll
            for (int j = 0; j < 4; ++j) {
                float h = ah[j];
                float xo = h + tanh_fast(h);
                // D layout: row = lg*4+j, col = ncol2
                x_lds[lg*4 + j][ncol2] = f2bf(xo);
            }
            __syncthreads();
        } else {
            const float wc = wcomb_lds[ncol2];
            #pragma unroll
            for (int j = 0; j < 4; ++j) {
                float h = ah[j];
                pool_acc += (h + tanh_fast(h)) * wc;
            }
        }
    }

    // ---- block reduce -> partial[blk] ----
    float* red = (float*)&p_lds[0][0];
    red[t] = pool_acc;
    __syncthreads();
    #pragma unroll
    for (int s = 256; s > 0; s >>= 1) {
        if (t < s) red[t] += red[t + s];
        __syncthreads();
    }
    if (t == 0) partial[blk] = red[0];
}

// ---- final: out[b] = out_b + out_w.fc0_b + sum of 8 group partials ----
__global__ void final_kernel(const float* __restrict__ partial,
                             const float* __restrict__ fc0_b,
                             const float* __restrict__ out_w,
                             const float* __restrict__ out_b,
                             float* __restrict__ out) {
    int b = threadIdx.x;  // 0..63
    float s = 0.f;
    #pragma unroll
    for (int k = 0; k < 8; ++k) s += partial[b*8 + k];
    float bb = out_b[0];
    #pragma unroll 16
    for (int c = 0; c < 256; ++c) bb += out_w[c] * fc0_b[c];
    out[b] = bb + s;
}

extern "C" void kernel_launch(void* const* d_in, const int* in_sizes, int n_in,
                              void* d_out, int out_size, void* d_ws, size_t ws_size,
                              hipStream_t stream) {
    const float* x     = (const float*)d_in[0];
    const float* dist  = (const float*)d_in[1];
    const float* wcf_w = (const float*)d_in[2];
    const float* wcf_b = (const float*)d_in[3];
    const float* wdf_w = (const float*)d_in[4];
    const float* wdf_b = (const float*)d_in[5];
    const float* wfc_w = (const float*)d_in[6];
    const float* fc0_w = (const float*)d_in[7];
    const float* fc0_b = (const float*)d_in[8];
    const float* out_w = (const float*)d_in[9];
    const float* out_b = (const float*)d_in[10];
    float* out = (float*)d_out;

    float* partial = (float*)d_ws;   // 512 floats, fully written by mega each call

    mega_kernel<<<NBLK, 512, 0, stream>>>(x, dist, wcf_w, wcf_b, wdf_w, wdf_b,
                                          wfc_w, fc0_w, out_w, partial);
    final_kernel<<<1, 64, 0, stream>>>(partial, fc0_b, out_w, out_b, out);
}

// Round 6
// 63.858 us; speedup vs baseline: 9.9022x; 1.7223x over previous
//
#include <hip/hip_runtime.h>
#include <math.h>

#define B_ 64
#define N_ 128
#define F_ 128
#define R_ 64
#define H_ 256
#define L_ 3
#define M_ (B_*N_)   // 8192 rows

#define DS_PAD 72    // ds_lds row stride (shorts), 144 B
#define X_PAD 136    // x_lds row stride, 272 B
#define P_PAD 264    // p_lds row stride, 528 B

#define PREPW_NBLK 48
#define COMB_BID   48
#define DSUM_BID0  49

typedef short bf16x8 __attribute__((ext_vector_type(8)));
typedef float f32x4 __attribute__((ext_vector_type(4)));

__device__ __forceinline__ unsigned short f2bf(float f) {
    unsigned int u = __float_as_uint(f);
    u += 0x7FFF + ((u >> 16) & 1);   // round-to-nearest-even
    return (unsigned short)(u >> 16);
}

__device__ __forceinline__ float tanh_fast(float h) {
    float a = fabsf(h);
    float e = __expf(-2.0f * a);
    float t = (1.0f - e) * __builtin_amdgcn_rcpf(1.0f + e);
    return copysignf(t, h);
}

// ---- kernel 1: dsum (8192 row-blocks) + weight prep (48 blocks) + comb/out-init (1 block) ----
// (verified structure from round 3 — do not disturb)
__global__ __launch_bounds__(256)
void dsum_prep_kernel(const float* __restrict__ dist,
                      const float* __restrict__ wcf,
                      const float* __restrict__ wdf,
                      const float* __restrict__ wfc,
                      const float* __restrict__ fc0_w, const float* __restrict__ fc0_b,
                      const float* __restrict__ out_w, const float* __restrict__ out_b,
                      unsigned short* __restrict__ wcfb,
                      unsigned short* __restrict__ wdfb,
                      unsigned short* __restrict__ wfcb,
                      float* __restrict__ wcomb,
                      unsigned short* __restrict__ dsumb,
                      float* __restrict__ out) {
    const int bid = blockIdx.x;
    const int t   = threadIdx.x;

    if (bid < PREPW_NBLK) {
        const int NCF = L_*H_*F_/4;  // 24576 float4
        const int NDF = L_*H_*R_/4;  // 12288
        const int NFC = L_*F_*H_/4;  // 24576
        const int total = NCF + NDF + NFC;
        for (int i = bid*256 + t; i < total; i += PREPW_NBLK*256) {
            const float4* src; unsigned short* dst; int k;
            if (i < NCF)           { src = (const float4*)wcf; dst = wcfb; k = i; }
            else if (i < NCF+NDF)  { src = (const float4*)wdf; dst = wdfb; k = i-NCF; }
            else                   { src = (const float4*)wfc; dst = wfcb; k = i-NCF-NDF; }
            float4 v = src[k];
            ushort4 o; o.x=f2bf(v.x); o.y=f2bf(v.y); o.z=f2bf(v.z); o.w=f2bf(v.w);
            ((ushort4*)dst)[k] = o;
        }
        return;
    }
    if (bid == COMB_BID) {
        if (t < 128) {
            float s = 0.f;
            #pragma unroll 8
            for (int c = 0; c < 256; ++c) s += out_w[c] * fc0_w[c*128 + t];
            wcomb[t] = s;
        } else if (t < 192) {
            float bb = out_b[0];
            #pragma unroll 8
            for (int c = 0; c < 256; ++c) bb += out_w[c] * fc0_b[c];
            out[t - 128] = bb;   // init; layers kernel atomicAdds on top
        }
        return;
    }

    // dsum for one row: dsumb[row,r] = sum_j dist[row,j,r]
    const int row = bid - DSUM_BID0;
    const float4* src = (const float4*)(dist + (size_t)row * (N_*R_));
    const int q = t & 15, jg = t >> 4;
    float4 a = make_float4(0.f,0.f,0.f,0.f);
    #pragma unroll
    for (int j0 = 0; j0 < N_; j0 += 16) {
        float4 v = src[(j0 + jg)*16 + q];
        a.x += v.x; a.y += v.y; a.z += v.z; a.w += v.w;
    }
    __shared__ float4 sh[256];
    sh[t] = a;
    __syncthreads();
    if (t < 16) {
        float4 s = sh[t];
        for (int g = 1; g < 16; ++g) {
            float4 v = sh[t + 16*g];
            s.x += v.x; s.y += v.y; s.z += v.z; s.w += v.w;
        }
        ushort4 o; o.x=f2bf(s.x); o.y=f2bf(s.y); o.z=f2bf(s.z); o.w=f2bf(s.w);
        ((ushort4*)(dsumb + (size_t)row * R_))[t] = o;
    }
}

// ---- kernel 2: fused 3 DTNN layers + pooled partial; 32 rows/block, 8 waves ----
// B-fragments loaded ONCE per wave and applied to both 16-row halves (12:24, 8:16 load:MFMA).
__global__ __launch_bounds__(512)
void layers_kernel(const float* __restrict__ x,
                   const unsigned short* __restrict__ dsumb,
                   const unsigned short* __restrict__ wcfb,
                   const unsigned short* __restrict__ wdfb,
                   const unsigned short* __restrict__ wfcb,
                   const float* __restrict__ biascf,
                   const float* __restrict__ biasdf,
                   const float* __restrict__ wcomb,
                   float* __restrict__ out) {
    __shared__ __align__(16) unsigned short ds_lds[32][DS_PAD];
    __shared__ __align__(16) unsigned short x_lds[32][X_PAD];
    __shared__ __align__(16) unsigned short p_lds[32][P_PAD];

    const int g    = blockIdx.x;               // 32-row group
    const int t    = threadIdx.x;
    const int w    = t >> 6, lane = t & 63;
    const int lr   = lane & 15, lg = lane >> 4;

    // load x (fp32 -> bf16) and dsum (bf16) into LDS
    {
        const int row16 = t >> 4, q = t & 15;
        const float4* xs = (const float4*)(x + (size_t)(g*32 + row16)*F_ + q*8);
        float4 xv0 = xs[0], xv1 = xs[1];
        bf16x8 xb;
        xb[0]=f2bf(xv0.x); xb[1]=f2bf(xv0.y); xb[2]=f2bf(xv0.z); xb[3]=f2bf(xv0.w);
        xb[4]=f2bf(xv1.x); xb[5]=f2bf(xv1.y); xb[6]=f2bf(xv1.z); xb[7]=f2bf(xv1.w);
        *(bf16x8*)&x_lds[row16][q*8] = xb;
        if (t < 256) {
            const uint4* dsrc = (const uint4*)(dsumb + (size_t)(g*32 + (t>>3))*R_);
            uint4 v = dsrc[t & 7];
            *(uint4*)&ds_lds[t>>3][(t&7)*8] = v;
        }
    }
    __syncthreads();

    float pool_acc = 0.f;

    #pragma unroll 1
    for (int l = 0; l < L_; ++l) {
        const unsigned short* wcf = wcfb + l*H_*F_;
        const unsigned short* wdf = wdfb + l*H_*R_;
        const unsigned short* wfc = wfcb + l*F_*H_;

        // A-fragments for BOTH 16-row halves
        bf16x8 xa[2][4], da[2][2];
        #pragma unroll
        for (int mh = 0; mh < 2; ++mh) {
            #pragma unroll
            for (int kc = 0; kc < 4; ++kc)
                xa[mh][kc] = *(const bf16x8*)&x_lds[mh*16 + lr][kc*32 + lg*8];
            #pragma unroll
            for (int kc = 0; kc < 2; ++kc)
                da[mh][kc] = *(const bf16x8*)&ds_lds[mh*16 + lr][kc*32 + lg*8];
        }

        // stage 1: wave owns H-cols [w*32, w*32+32); B-frags loaded once, used by both halves
        #pragma unroll
        for (int nt = 0; nt < 2; ++nt) {
            const int ncol = w*32 + nt*16 + lr;
            bf16x8 bcfv[4], bdfv[2];
            #pragma unroll
            for (int kc = 0; kc < 4; ++kc)
                bcfv[kc] = *(const bf16x8*)(wcf + (size_t)ncol*F_ + kc*32 + lg*8);
            #pragma unroll
            for (int kc = 0; kc < 2; ++kc)
                bdfv[kc] = *(const bf16x8*)(wdf + (size_t)ncol*R_ + kc*32 + lg*8);
            const float bc = biascf[l*H_ + ncol];
            const float bd = biasdf[l*H_ + ncol] * 128.0f;   // n * Wdf_b, n = 128
            #pragma unroll
            for (int mh = 0; mh < 2; ++mh) {
                f32x4 acf = {0.f,0.f,0.f,0.f}, adf = {0.f,0.f,0.f,0.f};
                #pragma unroll
                for (int kc = 0; kc < 4; ++kc)
                    acf = __builtin_amdgcn_mfma_f32_16x16x32_bf16(xa[mh][kc], bcfv[kc], acf, 0, 0, 0);
                #pragma unroll
                for (int kc = 0; kc < 2; ++kc)
                    adf = __builtin_amdgcn_mfma_f32_16x16x32_bf16(da[mh][kc], bdfv[kc], adf, 0, 0, 0);
                #pragma unroll
                for (int j = 0; j < 4; ++j) {
                    float p = (acf[j] + bc) * (adf[j] + bd);
                    p_lds[mh*16 + lg*4 + j][ncol] = f2bf(p);
                }
            }
        }
        __syncthreads();

        // stage 2: wave owns F-cols [w*16, w*16+16); one B-load feeds both halves
        const int ncol2 = w*16 + lr;
        f32x4 ah[2] = {{0,0,0,0},{0,0,0,0}};
        #pragma unroll
        for (int kc = 0; kc < 8; ++kc) {
            bf16x8 b = *(const bf16x8*)(wfc + (size_t)ncol2*H_ + kc*32 + lg*8);
            #pragma unroll
            for (int mh = 0; mh < 2; ++mh) {
                bf16x8 ap = *(const bf16x8*)&p_lds[mh*16 + lr][kc*32 + lg*8];
                ah[mh] = __builtin_amdgcn_mfma_f32_16x16x32_bf16(ap, b, ah[mh], 0, 0, 0);
            }
        }
        __syncthreads();   // p_lds consumed

        if (l < L_-1) {
            #pragma unroll
            for (int mh = 0; mh < 2; ++mh)
                #pragma unroll
                for (int j = 0; j < 4; ++j) {
                    float h = ah[mh][j];
                    float xo = h + tanh_fast(h);
                    x_lds[mh*16 + lg*4 + j][ncol2] = f2bf(xo);
                }
            __syncthreads();
        } else {
            const float wc = wcomb[ncol2];
            #pragma unroll
            for (int mh = 0; mh < 2; ++mh)
                #pragma unroll
                for (int j = 0; j < 4; ++j) {
                    float h = ah[mh][j];
                    pool_acc += (h + tanh_fast(h)) * wc;
                }
        }
    }

    // block reduce + one atomicAdd per block into out[b]  (4 groups per batch)
    float* red = (float*)&p_lds[0][0];
    red[t] = pool_acc;
    __syncthreads();
    #pragma unroll
    for (int s = 256; s > 0; s >>= 1) {
        if (t < s) red[t] += red[t + s];
        __syncthreads();
    }
    if (t == 0) atomicAdd(&out[g >> 2], red[0]);
}

extern "C" void kernel_launch(void* const* d_in, const int* in_sizes, int n_in,
                              void* d_out, int out_size, void* d_ws, size_t ws_size,
                              hipStream_t stream) {
    const float* x     = (const float*)d_in[0];
    const float* dist  = (const float*)d_in[1];
    const float* wcf_w = (const float*)d_in[2];
    const float* wcf_b = (const float*)d_in[3];
    const float* wdf_w = (const float*)d_in[4];
    const float* wdf_b = (const float*)d_in[5];
    const float* wfc_w = (const float*)d_in[6];
    const float* fc0_w = (const float*)d_in[7];
    const float* fc0_b = (const float*)d_in[8];
    const float* out_w = (const float*)d_in[9];
    const float* out_b = (const float*)d_in[10];
    float* out = (float*)d_out;

    char* ws = (char*)d_ws;
    unsigned short* wcfb  = (unsigned short*)(ws);                  // 196608 B
    unsigned short* wdfb  = (unsigned short*)(ws + 196608u);        //  98304 B
    unsigned short* wfcb  = (unsigned short*)(ws + 294912u);        // 196608 B
    float*          wcomb = (float*)(ws + 491520u);                 //    512 B
    unsigned short* dsumb = (unsigned short*)(ws + 492032u);        // 1 MB

    dsum_prep_kernel<<<DSUM_BID0 + M_, 256, 0, stream>>>(
        dist, wcf_w, wdf_w, wfc_w, fc0_w, fc0_b, out_w, out_b,
        wcfb, wdfb, wfcb, wcomb, dsumb, out);

    layers_kernel<<<M_/32, 512, 0, stream>>>(x, dsumb, wcfb, wdfb, wfcb,
                                             wcf_b, wdf_b, wcomb, out);
}